// Round 1
// baseline (967.724 us; speedup 1.0000x reference)
//
#include <hip/hip_runtime.h>

// ---------------------------------------------------------------------------
// GraphAllEdgeNet on MI355X — round 3:
//   * stage0 moved to bf16 MFMA (wf0 pre-laid A-fragments; x converted on the
//     fly to B-fragments). s0 is now memory-bound on the 204.8 MB x read.
//   * GEMM2 hoisted out of msg_pass via linearity of the mean:
//       mean_e(relu(bn2(h_e)) @ W2) = mean_e(relu(bn2(h_e))) @ W2
//     bn2 SCALE is folded into wf1 columns at prep time; msg_pass now stores
//     z = relu(h*s2 + b2) per edge; aggregate does segmented mean -> per-node
//     16x16x32 GEMM2 -> +resid -> BN/ReLU, one wave per 16 dst nodes.
// MFMA layout (measured): mfma_f32_16x16x32_bf16
//   A[m=lane&15][k=(lane>>4)*8+j], B[k=(lane>>4)*8+j][n=lane&15],
//   C/D: col=lane&15, row=(lane>>4)*4+reg.
// ---------------------------------------------------------------------------

#define NN 100000
#define NE 800000
#define NB 391                 // ceil(NN/256)
#define BNS 0.9999950000374998f

typedef __attribute__((ext_vector_type(8))) short short8;
typedef __attribute__((ext_vector_type(4))) float f32x4;

__device__ __forceinline__ float bf_lo(unsigned u){ union{unsigned i; float f;} v; v.i = u << 16; return v.f; }
__device__ __forceinline__ float bf_hi(unsigned u){ union{unsigned i; float f;} v; v.i = u & 0xffff0000u; return v.f; }
__device__ __forceinline__ float bf2f(unsigned short u){ union{unsigned i; float f;} v; v.i = ((unsigned)u) << 16; return v.f; }
__device__ __forceinline__ unsigned short f2bf(float f){
  union{float f; unsigned i;} v; v.f = f;
  unsigned r = v.i + 0x7fffu + ((v.i >> 16) & 1u);   // RNE
  return (unsigned short)(r >> 16);
}
__device__ __forceinline__ unsigned packbf(float a, float b){
  return (unsigned)f2bf(a) | ((unsigned)f2bf(b) << 16);
}

// ---------------- preprocessing -------------------------------------------

__global__ __launch_bounds__(256) void hist_kernel(
    const int* __restrict__ ei, const int* __restrict__ edel,
    const int* __restrict__ esel, int* cnt1, int* cnt2)
{
  int e = blockIdx.x * 256 + threadIdx.x;
  if (e >= NE) return;
  int d = edel[e], s = esel[e], dst = ei[NE + e];
  if (d < 1) atomicAdd(cnt1 + dst, 1);
  if ((d >= 1 && d < 4) || s == 1) atomicAdd(cnt2 + dst, 1);
}

// block-local exclusive scan of cnt -> row ; block totals -> bsum
__global__ __launch_bounds__(256) void scan1_kernel(
    const int* __restrict__ cnt1, const int* __restrict__ cnt2,
    int* row1, int* row2, int* bsum)
{
  const int a = blockIdx.y;
  const int* cnt = a ? cnt2 : cnt1;
  int* row = a ? row2 : row1;
  int t = threadIdx.x, b = blockIdx.x, i = b * 256 + t;
  int v = (i < NN) ? cnt[i] : 0;
  __shared__ int sc[256];
  sc[t] = v; __syncthreads();
#pragma unroll
  for (int off = 1; off < 256; off <<= 1){
    int x = (t >= off) ? sc[t - off] : 0;
    __syncthreads();
    sc[t] += x;
    __syncthreads();
  }
  if (i < NN) row[i] = sc[t] - v;
  if (t == 255) bsum[a * 400 + b] = sc[t];
}

// scan the 391 block totals for both arrays; totals -> ctr[0..1]
__global__ __launch_bounds__(512) void scan2_kernel(int* bsum, int* boff, int* ctr)
{
  int t = threadIdx.x;
  __shared__ int sc[512];
  for (int a = 0; a < 2; a++){
    int v = (t < NB) ? bsum[a * 400 + t] : 0;
    __syncthreads();
    sc[t] = v; __syncthreads();
#pragma unroll
    for (int off = 1; off < 512; off <<= 1){
      int x = (t >= off) ? sc[t - off] : 0;
      __syncthreads();
      sc[t] += x;
      __syncthreads();
    }
    if (t < NB) boff[a * 400 + t] = sc[t] - v;
    if (t == NB - 1) ctr[a] = sc[t];
  }
}

__global__ __launch_bounds__(256) void scan3_kernel(
    int* row1, int* row2, int* cur1, int* cur2, const int* __restrict__ boff)
{
  const int a = blockIdx.y;
  int* row = a ? row2 : row1;
  int* cur = a ? cur2 : cur1;
  int i = blockIdx.x * 256 + threadIdx.x;
  if (i >= NN) return;
  int r = row[i] + boff[a * 400 + blockIdx.x];
  row[i] = r;
  cur[i] = r;
}

__global__ __launch_bounds__(256) void inv_kernel(
    const int* __restrict__ cnt1, const int* __restrict__ cnt2,
    float* inv1, float* inv2)
{
  int i = blockIdx.x * 256 + threadIdx.x;
  if (i >= NN) return;
  inv1[i] = 1.f / fmaxf((float)cnt1[i], 1.f);
  inv2[i] = 1.f / fmaxf((float)cnt2[i], 1.f);
}

__global__ __launch_bounds__(256) void compact_kernel(
    const int* __restrict__ ei, const int* __restrict__ edel,
    const int* __restrict__ esel, int* cur1, int* cur2,
    int* s1s, int* s1d, int* s2s, int* s2d)
{
  int e = blockIdx.x * 256 + threadIdx.x;
  if (e >= NE) return;
  int d = edel[e], s = esel[e], src = ei[e], dst = ei[NE + e];
  if (d < 1){ int p = atomicAdd(cur1 + dst, 1); s1s[p] = src; s1d[p] = dst; }
  if ((d >= 1 && d < 4) || s == 1){ int p = atomicAdd(cur2 + dst, 1); s2s[p] = src; s2d[p] = dst; }
}

// pre-convert W1cat / W2 into MFMA A-fragment-layout bf16.
// wf1: [k][frag f=t*4+h][lane][8]  -- bn2 SCALE folded into columns
// wf2: [k][frag f=t*2+h][lane][8]
__global__ __launch_bounds__(256) void prep_w(
    const float* __restrict__ W1, const float* __restrict__ W2,
    const float* __restrict__ g2, unsigned short* __restrict__ wf1,
    unsigned short* __restrict__ wf2)
{
  int g = blockIdx.x * 256 + threadIdx.x;
  if (g >= 6144) return;
  int k = g / 1536, r = g % 1536, f = r >> 6, l = r & 63;
  int q = l >> 4, m = l & 15;
  if (f < 16){
    int t = f >> 2, h = f & 3;
    unsigned short* o = wf1 + (((size_t)k * 16 + f) * 64 + l) * 8;
    const float* Wk = W1 + k * 8192;
    int cp = t * 16 + m;
    float sc = BNS * g2[k * 64 + cp];
#pragma unroll
    for (int j = 0; j < 8; j++){
      int kg = h * 32 + q * 8 + j;
      float w = (kg < 64) ? Wk[(64 + kg) * 64 + cp] : Wk[(kg - 64) * 64 + cp];
      o[j] = f2bf(w * sc);
    }
  } else {
    int f2 = f - 16, t = f2 >> 1, h = f2 & 1;
    unsigned short* o = wf2 + (((size_t)k * 8 + f2) * 64 + l) * 8;
    const float* Wk = W2 + k * 4096;
#pragma unroll
    for (int j = 0; j < 8; j++){
      int kg = h * 32 + q * 8 + j;
      o[j] = f2bf(Wk[kg * 64 + t * 16 + m]);
    }
  }
}

// pre-convert W0a/W0v into MFMA A-fragment bf16:
// wf0[tt][kstep 0..15][t 0..3][lane][8], A[m=l&15 -> col t*16+m][k=ks*32+(l>>4)*8+j]
__global__ __launch_bounds__(256) void prep_w0(
    const float* __restrict__ W0a, const float* __restrict__ W0v,
    unsigned short* __restrict__ wf0)
{
  int g = blockIdx.x * 256 + threadIdx.x;     // 8192 fragment rows
  if (g >= 8192) return;
  int l = g & 63, t = (g >> 6) & 3, ks = (g >> 8) & 15, tt = (g >> 12) & 1;
  const float* W = tt ? W0v : W0a;
  int c = t * 16 + (l & 15);
  int kb = ks * 32 + (l >> 4) * 8;
  unsigned short* o = wf0 + (size_t)g * 8;
#pragma unroll
  for (int j = 0; j < 8; j++) o[j] = f2bf(W[(kb + j) * 64 + c]);
}

// ---------------- stage 0: node projection (bf16 MFMA) --------------------
// One wave per 16 nodes; K=512 in 16 steps of 32; lane m16 = node, channels
// t*16 + q*4 + r. Epilogue folds bias+BN0+ReLU.

__global__ __launch_bounds__(256) void s0_kernel(
    const float* __restrict__ x,
    const float* __restrict__ b0a, const float* __restrict__ b0v,
    const float* __restrict__ bn0g, const float* __restrict__ bn0b,
    const unsigned short* __restrict__ wf0,
    unsigned short* __restrict__ Xb)
{
  const int tt = blockIdx.y;
  const int wv = threadIdx.x >> 6;
  const int l  = threadIdx.x & 63;
  const int q = l >> 4, m16 = l & 15;
  const int wid = blockIdx.x * 4 + wv;        // 0..3124 (50000/16 exact)
  if (wid >= 3125) return;
  const int node = wid * 16 + m16;            // per-lane node (B col / D col)
  const float* bias = tt ? b0v : b0a;

  // fused epilogue constants: v = acc*fs + ft, fs = BNS*g, ft = bias*fs + b
  float fs[4][4], ft[4][4];
#pragma unroll
  for (int t = 0; t < 4; t++)
#pragma unroll
    for (int r = 0; r < 4; r++){
      int c = t * 16 + q * 4 + r;
      float s = BNS * bn0g[c];
      fs[t][r] = s;
      ft[t][r] = bias[c] * s + bn0b[c];
    }

  const unsigned short* wbase = wf0 + (size_t)tt * 16 * 4 * 64 * 8;
  const float* xp = x + (size_t)(2 * node + tt) * 1024 + tt * 512 + q * 8;

  f32x4 acc[4];
#pragma unroll
  for (int t = 0; t < 4; t++) acc[t] = (f32x4){0.f, 0.f, 0.f, 0.f};

  for (int ks = 0; ks < 16; ks++){
    float4 xa = *(const float4*)(xp + ks * 32);
    float4 xb = *(const float4*)(xp + ks * 32 + 4);
    union { unsigned u[4]; short8 s; } bb;
    bb.u[0] = packbf(xa.x, xa.y);
    bb.u[1] = packbf(xa.z, xa.w);
    bb.u[2] = packbf(xb.x, xb.y);
    bb.u[3] = packbf(xb.z, xb.w);
    const unsigned short* wk = wbase + (size_t)ks * 4 * 64 * 8 + l * 8;
#pragma unroll
    for (int t = 0; t < 4; t++){
      short8 a = *(const short8*)(wk + t * 64 * 8);
      acc[t] = __builtin_amdgcn_mfma_f32_16x16x32_bf16(a, bb.s, acc[t], 0, 0, 0);
    }
  }

  const int i = 2 * node + tt;
  unsigned short* op = Xb + (size_t)i * 64 + (q << 2);
#pragma unroll
  for (int t = 0; t < 4; t++){
    float v0 = fmaxf(fmaf(acc[t][0], fs[t][0], ft[t][0]), 0.f);
    float v1 = fmaxf(fmaf(acc[t][1], fs[t][1], ft[t][1]), 0.f);
    float v2 = fmaxf(fmaf(acc[t][2], fs[t][2], ft[t][2]), 0.f);
    float v3 = fmaxf(fmaf(acc[t][3], fs[t][3], ft[t][3]), 0.f);
    uint2 w; w.x = packbf(v0, v1); w.y = packbf(v2, v3);
    *(uint2*)(op + t * 16) = w;
  }
}

// ---------------- Phase A: edge-message MFMA kernel -----------------------
// One wave per 16-edge chunk (grid-stride); GEMM1 only (bn2 scale folded into
// wf1); stores z = relu(h + b2) per edge (GEMM2 hoisted to aggregate).

__global__ __launch_bounds__(256) void msg_pass(
    const unsigned short* __restrict__ fin,
    const int* __restrict__ ssrc, const int* __restrict__ sdst,
    const int* __restrict__ Sp,
    const unsigned short* __restrict__ wf1,
    const float* __restrict__ bn1g, const float* __restrict__ bn1b,
    const float* __restrict__ bn2b,
    unsigned short* __restrict__ msg, int nwaves)
{
  const int l   = threadIdx.x & 63;
  const int wv  = threadIdx.x >> 6;
  const int q   = l >> 4;
  const int m16 = l & 15;
  const int ge  = l >> 2;          // gather: edge within chunk
  const int gc0 = (l & 3) << 4;    // gather: channel window base

  __shared__ unsigned short r_lds[4][16 * 136];   // [edge][128 + 8 pad] bf16
  unsigned short* rt = &r_lds[wv][0];

  // A-operand weight fragments (bn2-scale-folded), one 16B load each
  short8 a1[4][4];
#pragma unroll
  for (int t = 0; t < 4; t++)
#pragma unroll
    for (int h = 0; h < 4; h++)
      a1[t][h] = *(const short8*)(wf1 + (((size_t)(t * 4 + h)) * 64 + l) * 8);

  float s1a[16], t1a[16], s1b[16], t1b[16];
#pragma unroll
  for (int j = 0; j < 16; j++){
    s1a[j] = BNS * bn1g[gc0 + j];       t1a[j] = bn1b[gc0 + j];
    s1b[j] = BNS * bn1g[64 + gc0 + j];  t1b[j] = bn1b[64 + gc0 + j];
  }
  f32x4 t2v[4];                     // b2 bias only (scale folded into wf1)
#pragma unroll
  for (int t = 0; t < 4; t++)
#pragma unroll
    for (int r = 0; r < 4; r++)
      t2v[t][r] = bn2b[t * 16 + q * 4 + r];

  const int S = *Sp;
  const int nch = (S + 15) >> 4;
  const int wgid = (blockIdx.x << 2) + wv;

  for (int ch = wgid; ch < nch; ch += nwaves){
    // ---- gather + BN1/ReLU elementwise -> rcat tile in LDS
    int eg = ch * 16 + ge; if (eg > S - 1) eg = S - 1;
    int src = ssrc[eg];
    int dsn = sdst[eg];
    const uint4* ps = (const uint4*)(fin + src * 64 + gc0);
    const uint4* pd = (const uint4*)(fin + dsn * 64 + gc0);
    uint4 su0 = ps[0], su1 = ps[1];
    uint4 du0 = pd[0], du1 = pd[1];

    unsigned sa[8] = {su0.x,su0.y,su0.z,su0.w,su1.x,su1.y,su1.z,su1.w};
    unsigned da[8] = {du0.x,du0.y,du0.z,du0.w,du1.x,du1.y,du1.z,du1.w};
    unsigned rb[8], ra[8];
#pragma unroll
    for (int p = 0; p < 8; p++){
      float fd0 = bf_lo(da[p]), fd1 = bf_hi(da[p]);
      float d0 = bf_lo(sa[p]) - fd0, d1 = bf_hi(sa[p]) - fd1;
      float rb0 = fmaxf(fmaf(d0,  s1b[2*p],   t1b[2*p]),   0.f);
      float rb1 = fmaxf(fmaf(d1,  s1b[2*p+1], t1b[2*p+1]), 0.f);
      float ra0 = fmaxf(fmaf(fd0, s1a[2*p],   t1a[2*p]),   0.f);
      float ra1 = fmaxf(fmaf(fd1, s1a[2*p+1], t1a[2*p+1]), 0.f);
      rb[p] = packbf(rb0, rb1);
      ra[p] = packbf(ra0, ra1);
    }
    unsigned short* wr = rt + ge * 136 + gc0;
    { uint4 u; u.x=rb[0]; u.y=rb[1]; u.z=rb[2]; u.w=rb[3]; *(uint4*)(wr)      = u; }
    { uint4 u; u.x=rb[4]; u.y=rb[5]; u.z=rb[6]; u.w=rb[7]; *(uint4*)(wr + 8)  = u; }
    { uint4 u; u.x=ra[0]; u.y=ra[1]; u.z=ra[2]; u.w=ra[3]; *(uint4*)(wr + 64) = u; }
    { uint4 u; u.x=ra[4]; u.y=ra[5]; u.z=ra[6]; u.w=ra[7]; *(uint4*)(wr + 72) = u; }

    __builtin_amdgcn_wave_barrier();   // wave-synchronous LDS ordering

    // ---- GEMM1 (K=128, scale-folded) + b2/ReLU -> z store (bf16)
    const unsigned short* rrow = rt + m16 * 136 + q * 8;
    short8 b1[4];
#pragma unroll
    for (int h = 0; h < 4; h++) b1[h] = *(const short8*)(rrow + h * 32);

    int ee = ch * 16 + m16;
    bool valid = ee < S;
    unsigned short* mp = msg + (size_t)ee * 64 + (q << 2);
#pragma unroll
    for (int t = 0; t < 4; t++){
      f32x4 c = {0.f, 0.f, 0.f, 0.f};
      c = __builtin_amdgcn_mfma_f32_16x16x32_bf16(a1[t][0], b1[0], c, 0, 0, 0);
      c = __builtin_amdgcn_mfma_f32_16x16x32_bf16(a1[t][1], b1[1], c, 0, 0, 0);
      c = __builtin_amdgcn_mfma_f32_16x16x32_bf16(a1[t][2], b1[2], c, 0, 0, 0);
      c = __builtin_amdgcn_mfma_f32_16x16x32_bf16(a1[t][3], b1[3], c, 0, 0, 0);
      if (valid){
        uint2 w;
        w.x = packbf(fmaxf(c[0] + t2v[t][0], 0.f), fmaxf(c[1] + t2v[t][1], 0.f));
        w.y = packbf(fmaxf(c[2] + t2v[t][2], 0.f), fmaxf(c[3] + t2v[t][3], 0.f));
        *(uint2*)(mp + t * 16) = w;
      }
    }
    __builtin_amdgcn_wave_barrier();   // protect LDS reuse across chunks
  }
}

// ---------------- Phase B: CSR segmented mean + GEMM2 + resid + BN/ReLU ---
// One wave per 16 dst nodes: phase 1 = masked mean of z rows (4 lanes/node,
// 16 ch/lane) -> LDS tile; phase 2 = 16x16x32 MFMA GEMM2 + fused epilogue.

__global__ __launch_bounds__(256) void aggregate_kernel(
    const unsigned short* __restrict__ msg,
    const int* __restrict__ row, const int* __restrict__ cnt,
    const float* __restrict__ inv,
    const unsigned short* __restrict__ wf2,
    const unsigned short* resid,           // may alias outb (same-lane RMW)
    const float* __restrict__ bng, const float* __restrict__ bnb,
    unsigned short* outb, int hasres, int hasbn)
{
  const int l  = threadIdx.x & 63;
  const int wv = threadIdx.x >> 6;
  const int q = l >> 4, m16 = l & 15;
  const int ge = l >> 2, gc0 = (l & 3) << 4;
  const int chunk = (blockIdx.x << 2) + wv;
  if (chunk >= 6250) return;               // 100000/16 exact

  __shared__ unsigned short z_lds[4][16 * 72];
  unsigned short* zt = &z_lds[wv][0];

  // W2 A-fragments (issue early; L2-resident)
  short8 a2[4][2];
#pragma unroll
  for (int t = 0; t < 4; t++)
#pragma unroll
    for (int h = 0; h < 2; h++)
      a2[t][h] = *(const short8*)(wf2 + (((size_t)(t * 2 + h)) * 64 + l) * 8);

  // ---- phase 1: segmented mean over CSR rows
  int d = chunk * 16 + ge;
  int r0 = row[d], deg = cnt[d];
  float s[16];
#pragma unroll
  for (int j = 0; j < 16; j++) s[j] = 0.f;
  const unsigned short* mp = msg + (size_t)r0 * 64 + gc0;
  for (int j = 0; j < deg; j++){
    uint4 u0 = *(const uint4*)(mp);
    uint4 u1 = *(const uint4*)(mp + 8);
    mp += 64;
    unsigned ua[8] = {u0.x,u0.y,u0.z,u0.w,u1.x,u1.y,u1.z,u1.w};
#pragma unroll
    for (int p = 0; p < 8; p++){
      s[2*p]   += bf_lo(ua[p]);
      s[2*p+1] += bf_hi(ua[p]);
    }
  }
  float iv = inv[d];
  unsigned pk[8];
#pragma unroll
  for (int p = 0; p < 8; p++) pk[p] = packbf(s[2*p] * iv, s[2*p+1] * iv);
  unsigned short* wr = zt + ge * 72 + gc0;
  { uint4 u; u.x=pk[0]; u.y=pk[1]; u.z=pk[2]; u.w=pk[3]; *(uint4*)(wr)     = u; }
  { uint4 u; u.x=pk[4]; u.y=pk[5]; u.z=pk[6]; u.w=pk[7]; *(uint4*)(wr + 8) = u; }

  __builtin_amdgcn_wave_barrier();

  // ---- phase 2: out = mean_z @ W2 (+resid)(+BN,ReLU)
  const unsigned short* r2row = zt + m16 * 72 + q * 8;
  short8 b2[2];
  b2[0] = *(const short8*)(r2row);
  b2[1] = *(const short8*)(r2row + 32);

  const int dn = chunk * 16 + m16;
  unsigned short* op = outb + (size_t)dn * 64 + (q << 2);
#pragma unroll
  for (int t = 0; t < 4; t++){
    f32x4 c = {0.f, 0.f, 0.f, 0.f};
    c = __builtin_amdgcn_mfma_f32_16x16x32_bf16(a2[t][0], b2[0], c, 0, 0, 0);
    c = __builtin_amdgcn_mfma_f32_16x16x32_bf16(a2[t][1], b2[1], c, 0, 0, 0);
    float v0 = c[0], v1 = c[1], v2 = c[2], v3 = c[3];
    if (hasres){
      uint2 rv = *(const uint2*)(resid + (size_t)dn * 64 + t * 16 + (q << 2));
      v0 += bf_lo(rv.x); v1 += bf_hi(rv.x);
      v2 += bf_lo(rv.y); v3 += bf_hi(rv.y);
    }
    if (hasbn){
      f32x4 g = *(const f32x4*)(bng + t * 16 + (q << 2));
      f32x4 b = *(const f32x4*)(bnb + t * 16 + (q << 2));
      v0 = fmaxf(fmaf(v0, BNS * g[0], b[0]), 0.f);
      v1 = fmaxf(fmaf(v1, BNS * g[1], b[1]), 0.f);
      v2 = fmaxf(fmaf(v2, BNS * g[2], b[2]), 0.f);
      v3 = fmaxf(fmaf(v3, BNS * g[3], b[3]), 0.f);
    }
    uint2 w; w.x = packbf(v0, v1); w.y = packbf(v2, v3);
    *(uint2*)(op + t * 16) = w;
  }
}

// ---------------- heads ----------------------------------------------------

__global__ __launch_bounds__(256) void head_final(
    const unsigned short* __restrict__ Xb,
    const float* __restrict__ Wf, const float* __restrict__ bf,
    float* __restrict__ out)
{
  int i = (blockIdx.x << 2) + (threadIdx.x >> 6);
  if (i >= NN) return;
  int l = threadIdx.x & 63;
  float v = bf2f(Xb[i * 64 + l]);
  float2 w = *(const float2*)(Wf + l * 2);
  float p0 = v * w.x, p1 = v * w.y;
#pragma unroll
  for (int off = 32; off; off >>= 1){
    p0 += __shfl_xor(p0, off);
    p1 += __shfl_xor(p1, off);
  }
  if (l == 0){ out[i * 2] = p0 + bf[0]; out[i * 2 + 1] = p1 + bf[1]; }
}

__global__ __launch_bounds__(256) void head_av(
    const unsigned short* __restrict__ Xb,
    const float* __restrict__ Wa, const float* __restrict__ ba,
    const float* __restrict__ Wv, const float* __restrict__ bv,
    float* __restrict__ outA, float* __restrict__ outV)
{
  int i = (blockIdx.x << 2) + (threadIdx.x >> 6);
  if (i >= NN) return;
  int l = threadIdx.x & 63;
  const float* Wf = (i & 1) ? Wv : Wa;
  const float* bb = (i & 1) ? bv : ba;
  float* o = (i & 1) ? (outV + (i >> 1) * 2) : (outA + (i >> 1) * 2);
  float v = bf2f(Xb[i * 64 + l]);
  float2 w = *(const float2*)(Wf + l * 2);
  float p0 = v * w.x, p1 = v * w.y;
#pragma unroll
  for (int off = 32; off; off >>= 1){
    p0 += __shfl_xor(p0, off);
    p1 += __shfl_xor(p1, off);
  }
  if (l == 0){ o[0] = p0 + bb[0]; o[1] = p1 + bb[1]; }
}

// ---------------- launcher -------------------------------------------------

extern "C" void kernel_launch(void* const* d_in, const int* in_sizes, int n_in,
                              void* d_out, int out_size, void* d_ws, size_t ws_size,
                              hipStream_t stream)
{
  const float* x    = (const float*)d_in[0];
  const int*   ei   = (const int*)d_in[1];
  const int*   edel = (const int*)d_in[2];
  const int*   esel = (const int*)d_in[3];
  // d_in[4] audio_node_mask: structurally (i%2==0); parity used directly.
  const float* W0a  = (const float*)d_in[5];
  const float* b0a  = (const float*)d_in[6];
  const float* W0v  = (const float*)d_in[7];
  const float* b0v  = (const float*)d_in[8];
  const float* bn0g = (const float*)d_in[9];
  const float* bn0b = (const float*)d_in[10];
  const float* ec1g = (const float*)d_in[11];
  const float* ec1b = (const float*)d_in[12];
  const float* ecW1 = (const float*)d_in[13];
  const float* ec2g = (const float*)d_in[14];
  const float* ec2b = (const float*)d_in[15];
  const float* ecW2 = (const float*)d_in[16];
  const float* bng  = (const float*)d_in[17];
  const float* bnb  = (const float*)d_in[18];
  const float* fcaW = (const float*)d_in[19];
  const float* fcab = (const float*)d_in[20];
  const float* fcvW = (const float*)d_in[21];
  const float* fcvb = (const float*)d_in[22];
  const float* fcW  = (const float*)d_in[23];
  const float* fcb  = (const float*)d_in[24];
  float* out = (float*)d_out;

  char* ws = (char*)d_ws;
  unsigned short* msg  = (unsigned short*)(ws + 0);            // 102,400,000
  unsigned short* Xb   = (unsigned short*)(ws + 102400000);    //  12,800,000
  unsigned short* Yb   = (unsigned short*)(ws + 115200000);    //  12,800,000
  int*            s1s  = (int*)(ws + 128000000);               //   3,200,000
  int*            s1d  = (int*)(ws + 131200000);
  int*            s2s  = (int*)(ws + 134400000);
  int*            s2d  = (int*)(ws + 137600000);
  int*            cnt1 = (int*)(ws + 140800000);               //     400,000
  int*            cnt2 = (int*)(ws + 141200000);
  int*            row1 = (int*)(ws + 141600000);
  int*            row2 = (int*)(ws + 142000000);
  int*            cur1 = (int*)(ws + 142400000);
  int*            cur2 = (int*)(ws + 142800000);
  float*          inv1 = (float*)(ws + 143200000);
  float*          inv2 = (float*)(ws + 143600000);
  int*            bsum = (int*)(ws + 144000000);               //       3,200
  int*            boff = (int*)(ws + 144003200);               //       3,200
  int*            ctr  = (int*)(ws + 144006400);               //          64
  unsigned short* wf1  = (unsigned short*)(ws + 144006464);    //      65,536
  unsigned short* wf2  = (unsigned short*)(ws + 144072000);    //      32,768
  // total: 144,104,768 bytes
  // wf0 (131,072 B) ALIASES the head of msg: it is consumed only by s0_kernel,
  // which completes (stream order) before the first msg_pass writes msg.
  unsigned short* wf0  = (unsigned short*)(ws + 0);

  // zero only the histogram counters
  hipMemsetAsync(cnt1, 0, 800000, stream);

  hist_kernel<<<(NE + 255) / 256, 256, 0, stream>>>(ei, edel, esel, cnt1, cnt2);
  scan1_kernel<<<dim3(NB, 2), 256, 0, stream>>>(cnt1, cnt2, row1, row2, bsum);
  scan2_kernel<<<1, 512, 0, stream>>>(bsum, boff, ctr);
  scan3_kernel<<<dim3(NB, 2), 256, 0, stream>>>(row1, row2, cur1, cur2, boff);
  inv_kernel<<<NB, 256, 0, stream>>>(cnt1, cnt2, inv1, inv2);
  compact_kernel<<<(NE + 255) / 256, 256, 0, stream>>>(ei, edel, esel, cur1, cur2,
                                                       s1s, s1d, s2s, s2d);
  prep_w<<<24, 256, 0, stream>>>(ecW1, ecW2, ec2g, wf1, wf2);
  prep_w0<<<32, 256, 0, stream>>>(W0a, W0v, wf0);

  s0_kernel<<<dim3(782, 2), 256, 0, stream>>>(x, b0a, b0v, bn0g, bn0b, wf0, Xb);
  head_av<<<25000, 256, 0, stream>>>(Xb, fcaW, fcab, fcvW, fcvb,
                                     out + 2 * NN, out + 2 * NN + 100000);

  const int EB = 1024;          // 4 waves/block
  const int nwaves = EB * 4;
  const int AGB = 1563;         // ceil(6250 chunks / 4 waves)

  for (int k = 0; k < 4; k++){
    const unsigned short* w1k = wf1 + (size_t)k * 16 * 64 * 8;
    const unsigned short* w2k = wf2 + (size_t)k * 8 * 64 * 8;
    const float* g1p = ec1g + k * 128;
    const float* b1p = ec1b + k * 128;
    const float* b2p = ec2b + k * 64;

    msg_pass<<<EB, 256, 0, stream>>>(Xb, s1s, s1d, ctr + 0, w1k,
                                     g1p, b1p, b2p, msg, nwaves);
    aggregate_kernel<<<AGB, 256, 0, stream>>>(msg, row1, cnt1, inv1, w2k,
                                              nullptr, nullptr, nullptr,
                                              Yb, 0, 0);
    msg_pass<<<EB, 256, 0, stream>>>(Yb, s2s, s2d, ctr + 1, w1k,
                                     g1p, b1p, b2p, msg, nwaves);
    const unsigned short* resid = (k == 0) ? nullptr : Xb;
    const float* bg = (k < 3) ? (bng + k * 64) : nullptr;
    const float* bb = (k < 3) ? (bnb + k * 64) : nullptr;
    aggregate_kernel<<<AGB, 256, 0, stream>>>(msg, row2, cnt2, inv2, w2k,
                                              resid, bg, bb,
                                              Xb, (k == 0) ? 0 : 1, (k < 3) ? 1 : 0);
  }

  head_final<<<25000, 256, 0, stream>>>(Xb, fcW, fcb, out);
}

// Round 2
// 940.044 us; speedup vs baseline: 1.0294x; 1.0294x over previous
//
#include <hip/hip_runtime.h>

// ---------------------------------------------------------------------------
// GraphAllEdgeNet on MI355X — round 4: fully fused EdgeConv pass.
//   edge_pass = gather + BN1(bias)+ReLU -> GEMM1 (BN1/BN2 scales folded into
//   wf1) -> relu(+b2) -> CSR segmented mean (in-register, dst-sorted edges
//   are contiguous per 16-node chunk) -> GEMM2 -> +resid -> BN/ReLU -> store.
//   msg buffer eliminated; 16 loop dispatches -> 8.
//   wf1 staged in block LDS (frees 64 VGPR); xi rows staged per-wave in LDS
//   (halves gather: only src rows fetched per edge).
// MFMA layout (measured): mfma_f32_16x16x32_bf16
//   A[m=lane&15][k=(lane>>4)*8+j], B[k=(lane>>4)*8+j][n=lane&15],
//   C/D: col=lane&15, row=(lane>>4)*4+reg.
// ---------------------------------------------------------------------------

#define NN 100000
#define NE 800000
#define NB 391                 // ceil(NN/256)
#define BNS 0.9999950000374998f

typedef __attribute__((ext_vector_type(8))) short short8;
typedef __attribute__((ext_vector_type(4))) float f32x4;

__device__ __forceinline__ float bf_lo(unsigned u){ union{unsigned i; float f;} v; v.i = u << 16; return v.f; }
__device__ __forceinline__ float bf_hi(unsigned u){ union{unsigned i; float f;} v; v.i = u & 0xffff0000u; return v.f; }
__device__ __forceinline__ float bf2f(unsigned short u){ union{unsigned i; float f;} v; v.i = ((unsigned)u) << 16; return v.f; }
__device__ __forceinline__ unsigned short f2bf(float f){
  union{float f; unsigned i;} v; v.f = f;
  unsigned r = v.i + 0x7fffu + ((v.i >> 16) & 1u);   // RNE
  return (unsigned short)(r >> 16);
}
__device__ __forceinline__ unsigned packbf(float a, float b){
  return (unsigned)f2bf(a) | ((unsigned)f2bf(b) << 16);
}

// ---------------- preprocessing -------------------------------------------

__global__ __launch_bounds__(256) void hist_kernel(
    const int* __restrict__ ei, const int* __restrict__ edel,
    const int* __restrict__ esel, int* cnt1, int* cnt2)
{
  int e = blockIdx.x * 256 + threadIdx.x;
  if (e >= NE) return;
  int d = edel[e], s = esel[e], dst = ei[NE + e];
  if (d < 1) atomicAdd(cnt1 + dst, 1);
  if ((d >= 1 && d < 4) || s == 1) atomicAdd(cnt2 + dst, 1);
}

// block-local exclusive scan of cnt -> row ; block totals -> bsum
__global__ __launch_bounds__(256) void scan1_kernel(
    const int* __restrict__ cnt1, const int* __restrict__ cnt2,
    int* row1, int* row2, int* bsum)
{
  const int a = blockIdx.y;
  const int* cnt = a ? cnt2 : cnt1;
  int* row = a ? row2 : row1;
  int t = threadIdx.x, b = blockIdx.x, i = b * 256 + t;
  int v = (i < NN) ? cnt[i] : 0;
  __shared__ int sc[256];
  sc[t] = v; __syncthreads();
#pragma unroll
  for (int off = 1; off < 256; off <<= 1){
    int x = (t >= off) ? sc[t - off] : 0;
    __syncthreads();
    sc[t] += x;
    __syncthreads();
  }
  if (i < NN) row[i] = sc[t] - v;
  if (t == 255) bsum[a * 400 + b] = sc[t];
}

// scan the 391 block totals for both arrays; totals -> ctr[0..1]
__global__ __launch_bounds__(512) void scan2_kernel(int* bsum, int* boff, int* ctr)
{
  int t = threadIdx.x;
  __shared__ int sc[512];
  for (int a = 0; a < 2; a++){
    int v = (t < NB) ? bsum[a * 400 + t] : 0;
    __syncthreads();
    sc[t] = v; __syncthreads();
#pragma unroll
    for (int off = 1; off < 512; off <<= 1){
      int x = (t >= off) ? sc[t - off] : 0;
      __syncthreads();
      sc[t] += x;
      __syncthreads();
    }
    if (t < NB) boff[a * 400 + t] = sc[t] - v;
    if (t == NB - 1) ctr[a] = sc[t];
  }
}

__global__ __launch_bounds__(256) void scan3_kernel(
    int* row1, int* row2, int* cur1, int* cur2, const int* __restrict__ boff)
{
  const int a = blockIdx.y;
  int* row = a ? row2 : row1;
  int* cur = a ? cur2 : cur1;
  int i = blockIdx.x * 256 + threadIdx.x;
  if (i >= NN) return;
  int r = row[i] + boff[a * 400 + blockIdx.x];
  row[i] = r;
  cur[i] = r;
}

__global__ __launch_bounds__(256) void inv_kernel(
    const int* __restrict__ cnt1, const int* __restrict__ cnt2,
    float* inv1, float* inv2)
{
  int i = blockIdx.x * 256 + threadIdx.x;
  if (i >= NN) return;
  inv1[i] = 1.f / fmaxf((float)cnt1[i], 1.f);
  inv2[i] = 1.f / fmaxf((float)cnt2[i], 1.f);
}

// compacted edge record: src | (dst&15)<<20  (src < 2^17; chunk = dst>>4)
__global__ __launch_bounds__(256) void compact_kernel(
    const int* __restrict__ ei, const int* __restrict__ edel,
    const int* __restrict__ esel, int* cur1, int* cur2,
    int* s1s, int* s2s)
{
  int e = blockIdx.x * 256 + threadIdx.x;
  if (e >= NE) return;
  int d = edel[e], s = esel[e], src = ei[e], dst = ei[NE + e];
  int rec = src | ((dst & 15) << 20);
  if (d < 1){ int p = atomicAdd(cur1 + dst, 1); s1s[p] = rec; }
  if ((d >= 1 && d < 4) || s == 1){ int p = atomicAdd(cur2 + dst, 1); s2s[p] = rec; }
}

// pre-convert W1cat / W2 into MFMA A-fragment-layout bf16.
// wf1: [k][frag f=t*4+h][lane][8] -- BN1 row-scale AND BN2 col-scale folded.
// wf2: [k][frag f=t*2+h][lane][8]
// t1p: [k][128] = b1 / (BNS*g1)   (BN1 bias after scale-commute with relu)
__global__ __launch_bounds__(256) void prep_w(
    const float* __restrict__ W1, const float* __restrict__ W2,
    const float* __restrict__ g1, const float* __restrict__ g2,
    const float* __restrict__ b1,
    unsigned short* __restrict__ wf1, unsigned short* __restrict__ wf2,
    float* __restrict__ t1p)
{
  int g = blockIdx.x * 256 + threadIdx.x;
  if (g >= 6656) return;
  if (g >= 6144){                       // t1p part
    int i = g - 6144;                   // 0..511
    int k = i >> 7, c = i & 127;
    t1p[i] = b1[k * 128 + c] / (BNS * g1[k * 128 + c]);
    return;
  }
  int k = g / 1536, r = g % 1536, f = r >> 6, l = r & 63;
  int q = l >> 4, m = l & 15;
  if (f < 16){
    int t = f >> 2, h = f & 3;
    unsigned short* o = wf1 + (((size_t)k * 16 + f) * 64 + l) * 8;
    const float* Wk = W1 + k * 8192;
    int cp = t * 16 + m;
    float cs = BNS * g2[k * 64 + cp];
#pragma unroll
    for (int j = 0; j < 8; j++){
      int kg = h * 32 + q * 8 + j;      // GEMM K index 0..127
      float w, rs;
      if (kg < 64){                     // d-part: W1 row 64+kg, bn1 ch 64+kg
        w  = Wk[(64 + kg) * 64 + cp];
        rs = BNS * g1[k * 128 + 64 + kg];
      } else {                          // xi-part: W1 row kg-64, bn1 ch kg-64
        w  = Wk[(kg - 64) * 64 + cp];
        rs = BNS * g1[k * 128 + kg - 64];
      }
      o[j] = f2bf(w * rs * cs);
    }
  } else {
    int f2 = f - 16, t = f2 >> 1, h = f2 & 1;
    unsigned short* o = wf2 + (((size_t)k * 8 + f2) * 64 + l) * 8;
    const float* Wk = W2 + k * 4096;
#pragma unroll
    for (int j = 0; j < 8; j++){
      int kg = h * 32 + q * 8 + j;
      o[j] = f2bf(Wk[kg * 64 + t * 16 + m]);
    }
  }
}

// pre-convert W0a/W0v into MFMA A-fragment bf16:
// wf0[tt][kstep 0..15][t 0..3][lane][8]
__global__ __launch_bounds__(256) void prep_w0(
    const float* __restrict__ W0a, const float* __restrict__ W0v,
    unsigned short* __restrict__ wf0)
{
  int g = blockIdx.x * 256 + threadIdx.x;     // 8192 fragment rows
  if (g >= 8192) return;
  int l = g & 63, t = (g >> 6) & 3, ks = (g >> 8) & 15, tt = (g >> 12) & 1;
  const float* W = tt ? W0v : W0a;
  int c = t * 16 + (l & 15);
  int kb = ks * 32 + (l >> 4) * 8;
  unsigned short* o = wf0 + (size_t)g * 8;
#pragma unroll
  for (int j = 0; j < 8; j++) o[j] = f2bf(W[(kb + j) * 64 + c]);
}

// ---------------- stage 0: node projection (bf16 MFMA) --------------------

__global__ __launch_bounds__(256) void s0_kernel(
    const float* __restrict__ x,
    const float* __restrict__ b0a, const float* __restrict__ b0v,
    const float* __restrict__ bn0g, const float* __restrict__ bn0b,
    const unsigned short* __restrict__ wf0,
    unsigned short* __restrict__ Xb)
{
  const int tt = blockIdx.y;
  const int wv = threadIdx.x >> 6;
  const int l  = threadIdx.x & 63;
  const int q = l >> 4, m16 = l & 15;
  const int wid = blockIdx.x * 4 + wv;
  if (wid >= 3125) return;
  const int node = wid * 16 + m16;
  const float* bias = tt ? b0v : b0a;

  float fs[4][4], ft[4][4];
#pragma unroll
  for (int t = 0; t < 4; t++)
#pragma unroll
    for (int r = 0; r < 4; r++){
      int c = t * 16 + q * 4 + r;
      float s = BNS * bn0g[c];
      fs[t][r] = s;
      ft[t][r] = bias[c] * s + bn0b[c];
    }

  const unsigned short* wbase = wf0 + (size_t)tt * 16 * 4 * 64 * 8;
  const float* xp = x + (size_t)(2 * node + tt) * 1024 + tt * 512 + q * 8;

  f32x4 acc[4];
#pragma unroll
  for (int t = 0; t < 4; t++) acc[t] = (f32x4){0.f, 0.f, 0.f, 0.f};

  for (int ks = 0; ks < 16; ks++){
    float4 xa = *(const float4*)(xp + ks * 32);
    float4 xb = *(const float4*)(xp + ks * 32 + 4);
    union { unsigned u[4]; short8 s; } bb;
    bb.u[0] = packbf(xa.x, xa.y);
    bb.u[1] = packbf(xa.z, xa.w);
    bb.u[2] = packbf(xb.x, xb.y);
    bb.u[3] = packbf(xb.z, xb.w);
    const unsigned short* wk = wbase + (size_t)ks * 4 * 64 * 8 + l * 8;
#pragma unroll
    for (int t = 0; t < 4; t++){
      short8 a = *(const short8*)(wk + t * 64 * 8);
      acc[t] = __builtin_amdgcn_mfma_f32_16x16x32_bf16(a, bb.s, acc[t], 0, 0, 0);
    }
  }

  const int i = 2 * node + tt;
  unsigned short* op = Xb + (size_t)i * 64 + (q << 2);
#pragma unroll
  for (int t = 0; t < 4; t++){
    float v0 = fmaxf(fmaf(acc[t][0], fs[t][0], ft[t][0]), 0.f);
    float v1 = fmaxf(fmaf(acc[t][1], fs[t][1], ft[t][1]), 0.f);
    float v2 = fmaxf(fmaf(acc[t][2], fs[t][2], ft[t][2]), 0.f);
    float v3 = fmaxf(fmaf(acc[t][3], fs[t][3], ft[t][3]), 0.f);
    uint2 w; w.x = packbf(v0, v1); w.y = packbf(v2, v3);
    *(uint2*)(op + t * 16) = w;
  }
}

// ---------------- fused EdgeConv pass -------------------------------------
// One wave per 16 dst nodes. Edges are dst-sorted -> contiguous range.
// Per 16-edge tile: gather src rows + LDS xi -> BN1(bias)+ReLU -> GEMM1
// (scales pre-folded) -> relu(+b2) z-tile -> per-node in-register partial
// sums. Epilogue: *inv -> GEMM2 -> (+resid)(+BN,ReLU) -> store.

__global__ __launch_bounds__(256, 3) void edge_pass(
    const unsigned short* __restrict__ fin,
    const int* __restrict__ spk,
    const int* __restrict__ row, const int* __restrict__ cnt,
    const float* __restrict__ inv,
    const unsigned short* __restrict__ wf1,
    const unsigned short* __restrict__ wf2,
    const float* __restrict__ t1p,
    const float* __restrict__ bn2b,
    const unsigned short* resid,           // may alias outb (same-lane RMW)
    const float* __restrict__ bng, const float* __restrict__ bnb,
    unsigned short* __restrict__ outb, int hasres, int hasbn)
{
  const int tid = threadIdx.x;
  const int l = tid & 63;
  const int wv = tid >> 6;
  const int q = l >> 4, m16 = l & 15;
  const int ge = l >> 2, gc0 = (l & 3) << 4;

  __shared__ unsigned short wlds[8192];          // 16 KB wf1 tile (block)
  __shared__ unsigned short rt_s[4][16 * 136];   // B-tile  [edge][128+8]
  __shared__ unsigned short zt_s[4][16 * 72];    // z-tile  [edge][64+8]
  __shared__ unsigned short xi_s[4][16 * 72];    // raw xi  [node][64+8]

  // stage wf1 -> LDS (1024 uint4, 4 per thread)
  {
    const uint4* s4 = (const uint4*)wf1;
    uint4* d4 = (uint4*)wlds;
#pragma unroll
    for (int i = 0; i < 4; i++) d4[tid + 256 * i] = s4[tid + 256 * i];
  }
  __syncthreads();

  int chunk = blockIdx.x * 4 + wv;
  const bool active = chunk < 6250;
  if (chunk > 6249) chunk = 6249;
  const int d0 = chunk << 4;
  const int nd = d0 + ge;

  unsigned short* rt = rt_s[wv];
  unsigned short* zt = zt_s[wv];
  unsigned short* xi = xi_s[wv];

  // ---- per-node preamble: CSR bounds, biases, xi row -> LDS
  const int rlo = row[nd], deg = cnt[nd];
  const float ivd = inv[nd];

  float t1a[16], t1b[16];
#pragma unroll
  for (int j0 = 0; j0 < 16; j0 += 4){
    *(float4*)(t1a + j0) = *(const float4*)(t1p + gc0 + j0);
    *(float4*)(t1b + j0) = *(const float4*)(t1p + 64 + gc0 + j0);
  }
  f32x4 t2v[4];
#pragma unroll
  for (int t = 0; t < 4; t++)
    t2v[t] = *(const f32x4*)(bn2b + t * 16 + (q << 2));

  {
    const uint4* px = (const uint4*)(fin + (size_t)nd * 64 + gc0);
    uint4 u0 = px[0], u1 = px[1];
    unsigned short* wr = xi + ge * 72 + gc0;
    *(uint4*)(wr)     = u0;
    *(uint4*)(wr + 8) = u1;
  }

  const int r_begin = __shfl(rlo, 0);
  const int r_end   = __shfl(rlo + deg, 63);

  float s[16];
#pragma unroll
  for (int j = 0; j < 16; j++) s[j] = 0.f;

  __builtin_amdgcn_wave_barrier();   // xi_s visible to gather roles

  for (int e0 = r_begin; e0 < r_end; e0 += 16){
    // ---- gather src row; xi from LDS; BN1-bias + relu -> rt tile
    int eg = e0 + ge; if (eg >= r_end) eg = r_end - 1;
    unsigned v = (unsigned)spk[eg];
    int src = v & 0xFFFFF;
    int d15 = (v >> 20) & 15;
    const uint4* ps = (const uint4*)(fin + (size_t)src * 64 + gc0);
    uint4 su0 = ps[0], su1 = ps[1];
    const uint4* pxi = (const uint4*)(xi + d15 * 72 + gc0);
    uint4 xu0 = pxi[0], xu1 = pxi[1];

    unsigned sa[8] = {su0.x,su0.y,su0.z,su0.w,su1.x,su1.y,su1.z,su1.w};
    unsigned xa[8] = {xu0.x,xu0.y,xu0.z,xu0.w,xu1.x,xu1.y,xu1.z,xu1.w};
    unsigned rb[8], rc[8];
#pragma unroll
    for (int p = 0; p < 8; p++){
      float x0 = bf_lo(xa[p]), x1 = bf_hi(xa[p]);
      float e0f = bf_lo(sa[p]) - x0, e1f = bf_hi(sa[p]) - x1;
      rb[p] = packbf(fmaxf(e0f + t1b[2*p], 0.f), fmaxf(e1f + t1b[2*p+1], 0.f));
      rc[p] = packbf(fmaxf(x0 + t1a[2*p], 0.f),  fmaxf(x1 + t1a[2*p+1], 0.f));
    }
    unsigned short* wr = rt + ge * 136 + gc0;
    { uint4 u; u.x=rb[0]; u.y=rb[1]; u.z=rb[2]; u.w=rb[3]; *(uint4*)(wr)      = u; }
    { uint4 u; u.x=rb[4]; u.y=rb[5]; u.z=rb[6]; u.w=rb[7]; *(uint4*)(wr + 8)  = u; }
    { uint4 u; u.x=rc[0]; u.y=rc[1]; u.z=rc[2]; u.w=rc[3]; *(uint4*)(wr + 64) = u; }
    { uint4 u; u.x=rc[4]; u.y=rc[5]; u.z=rc[6]; u.w=rc[7]; *(uint4*)(wr + 72) = u; }

    __builtin_amdgcn_wave_barrier();

    // ---- GEMM1 (K=128, scales folded) + b2/relu -> z tile
    const unsigned short* rrow = rt + m16 * 136 + q * 8;
    short8 b1[4];
#pragma unroll
    for (int h = 0; h < 4; h++) b1[h] = *(const short8*)(rrow + h * 32);

#pragma unroll
    for (int t = 0; t < 4; t++){
      f32x4 c = {0.f, 0.f, 0.f, 0.f};
#pragma unroll
      for (int h = 0; h < 4; h++){
        short8 a = *(const short8*)(wlds + ((t * 4 + h) * 64 + l) * 8);
        c = __builtin_amdgcn_mfma_f32_16x16x32_bf16(a, b1[h], c, 0, 0, 0);
      }
      uint2 w;
      w.x = packbf(fmaxf(c[0] + t2v[t][0], 0.f), fmaxf(c[1] + t2v[t][1], 0.f));
      w.y = packbf(fmaxf(c[2] + t2v[t][2], 0.f), fmaxf(c[3] + t2v[t][3], 0.f));
      *(uint2*)(zt + m16 * 72 + t * 16 + (q << 2)) = w;
    }

    __builtin_amdgcn_wave_barrier();

    // ---- segmented accumulation (lane's node rows within this tile)
    int jlo = rlo - e0;       if (jlo < 0)  jlo = 0;
    int jhi = rlo + deg - e0; if (jhi > 16) jhi = 16;
    for (int j = jlo; j < jhi; j++){
      const uint4* pz = (const uint4*)(zt + j * 72 + gc0);
      uint4 z0 = pz[0], z1 = pz[1];
      unsigned za[8] = {z0.x,z0.y,z0.z,z0.w,z1.x,z1.y,z1.z,z1.w};
#pragma unroll
      for (int p = 0; p < 8; p++){
        s[2*p]   += bf_lo(za[p]);
        s[2*p+1] += bf_hi(za[p]);
      }
    }
    __builtin_amdgcn_wave_barrier();
  }

  // ---- epilogue: mean -> GEMM2 -> (+resid)(+BN,ReLU) -> store
  unsigned pk[8];
#pragma unroll
  for (int p = 0; p < 8; p++) pk[p] = packbf(s[2*p] * ivd, s[2*p+1] * ivd);
  unsigned short* wr = zt + ge * 72 + gc0;
  { uint4 u; u.x=pk[0]; u.y=pk[1]; u.z=pk[2]; u.w=pk[3]; *(uint4*)(wr)     = u; }
  { uint4 u; u.x=pk[4]; u.y=pk[5]; u.z=pk[6]; u.w=pk[7]; *(uint4*)(wr + 8) = u; }

  __builtin_amdgcn_wave_barrier();

  short8 a2[4][2];
#pragma unroll
  for (int t = 0; t < 4; t++)
#pragma unroll
    for (int h = 0; h < 2; h++)
      a2[t][h] = *(const short8*)(wf2 + (((size_t)(t * 2 + h)) * 64 + l) * 8);

  const unsigned short* r2row = zt + m16 * 72 + q * 8;
  short8 b2[2];
  b2[0] = *(const short8*)(r2row);
  b2[1] = *(const short8*)(r2row + 32);

  const int dn = d0 + m16;
  unsigned short* op = outb + (size_t)dn * 64 + (q << 2);
#pragma unroll
  for (int t = 0; t < 4; t++){
    f32x4 c = {0.f, 0.f, 0.f, 0.f};
    c = __builtin_amdgcn_mfma_f32_16x16x32_bf16(a2[t][0], b2[0], c, 0, 0, 0);
    c = __builtin_amdgcn_mfma_f32_16x16x32_bf16(a2[t][1], b2[1], c, 0, 0, 0);
    float v0 = c[0], v1 = c[1], v2 = c[2], v3 = c[3];
    if (hasres){
      uint2 rv = *(const uint2*)(resid + (size_t)dn * 64 + t * 16 + (q << 2));
      v0 += bf_lo(rv.x); v1 += bf_hi(rv.x);
      v2 += bf_lo(rv.y); v3 += bf_hi(rv.y);
    }
    if (hasbn){
      f32x4 g = *(const f32x4*)(bng + t * 16 + (q << 2));
      f32x4 b = *(const f32x4*)(bnb + t * 16 + (q << 2));
      v0 = fmaxf(fmaf(v0, BNS * g[0], b[0]), 0.f);
      v1 = fmaxf(fmaf(v1, BNS * g[1], b[1]), 0.f);
      v2 = fmaxf(fmaf(v2, BNS * g[2], b[2]), 0.f);
      v3 = fmaxf(fmaf(v3, BNS * g[3], b[3]), 0.f);
    }
    if (active){
      uint2 w; w.x = packbf(v0, v1); w.y = packbf(v2, v3);
      *(uint2*)(op + t * 16) = w;
    }
  }
}

// ---------------- heads ----------------------------------------------------

__global__ __launch_bounds__(256) void head_final(
    const unsigned short* __restrict__ Xb,
    const float* __restrict__ Wf, const float* __restrict__ bf,
    float* __restrict__ out)
{
  int i = (blockIdx.x << 2) + (threadIdx.x >> 6);
  if (i >= NN) return;
  int l = threadIdx.x & 63;
  float v = bf2f(Xb[i * 64 + l]);
  float2 w = *(const float2*)(Wf + l * 2);
  float p0 = v * w.x, p1 = v * w.y;
#pragma unroll
  for (int off = 32; off; off >>= 1){
    p0 += __shfl_xor(p0, off);
    p1 += __shfl_xor(p1, off);
  }
  if (l == 0){ out[i * 2] = p0 + bf[0]; out[i * 2 + 1] = p1 + bf[1]; }
}

__global__ __launch_bounds__(256) void head_av(
    const unsigned short* __restrict__ Xb,
    const float* __restrict__ Wa, const float* __restrict__ ba,
    const float* __restrict__ Wv, const float* __restrict__ bv,
    float* __restrict__ outA, float* __restrict__ outV)
{
  int i = (blockIdx.x << 2) + (threadIdx.x >> 6);
  if (i >= NN) return;
  int l = threadIdx.x & 63;
  const float* Wf = (i & 1) ? Wv : Wa;
  const float* bb = (i & 1) ? bv : ba;
  float* o = (i & 1) ? (outV + (i >> 1) * 2) : (outA + (i >> 1) * 2);
  float v = bf2f(Xb[i * 64 + l]);
  float2 w = *(const float2*)(Wf + l * 2);
  float p0 = v * w.x, p1 = v * w.y;
#pragma unroll
  for (int off = 32; off; off >>= 1){
    p0 += __shfl_xor(p0, off);
    p1 += __shfl_xor(p1, off);
  }
  if (l == 0){ o[0] = p0 + bb[0]; o[1] = p1 + bb[1]; }
}

// ---------------- launcher -------------------------------------------------

extern "C" void kernel_launch(void* const* d_in, const int* in_sizes, int n_in,
                              void* d_out, int out_size, void* d_ws, size_t ws_size,
                              hipStream_t stream)
{
  const float* x    = (const float*)d_in[0];
  const int*   ei   = (const int*)d_in[1];
  const int*   edel = (const int*)d_in[2];
  const int*   esel = (const int*)d_in[3];
  // d_in[4] audio_node_mask: structurally (i%2==0); parity used directly.
  const float* W0a  = (const float*)d_in[5];
  const float* b0a  = (const float*)d_in[6];
  const float* W0v  = (const float*)d_in[7];
  const float* b0v  = (const float*)d_in[8];
  const float* bn0g = (const float*)d_in[9];
  const float* bn0b = (const float*)d_in[10];
  const float* ec1g = (const float*)d_in[11];
  const float* ec1b = (const float*)d_in[12];
  const float* ecW1 = (const float*)d_in[13];
  const float* ec2g = (const float*)d_in[14];
  const float* ec2b = (const float*)d_in[15];
  const float* ecW2 = (const float*)d_in[16];
  const float* bng  = (const float*)d_in[17];
  const float* bnb  = (const float*)d_in[18];
  const float* fcaW = (const float*)d_in[19];
  const float* fcab = (const float*)d_in[20];
  const float* fcvW = (const float*)d_in[21];
  const float* fcvb = (const float*)d_in[22];
  const float* fcW  = (const float*)d_in[23];
  const float* fcb  = (const float*)d_in[24];
  float* out = (float*)d_out;

  char* ws = (char*)d_ws;
  unsigned short* Xb   = (unsigned short*)(ws + 102400000);    //  12,800,000
  unsigned short* Yb   = (unsigned short*)(ws + 115200000);    //  12,800,000
  int*            s1s  = (int*)(ws + 128000000);               //   3,200,000
  int*            s2s  = (int*)(ws + 134400000);
  int*            cnt1 = (int*)(ws + 140800000);               //     400,000
  int*            cnt2 = (int*)(ws + 141200000);
  int*            row1 = (int*)(ws + 141600000);
  int*            row2 = (int*)(ws + 142000000);
  int*            cur1 = (int*)(ws + 142400000);
  int*            cur2 = (int*)(ws + 142800000);
  float*          inv1 = (float*)(ws + 143200000);
  float*          inv2 = (float*)(ws + 143600000);
  int*            bsum = (int*)(ws + 144000000);               //       3,200
  int*            boff = (int*)(ws + 144003200);               //       3,200
  int*            ctr  = (int*)(ws + 144006400);               //          64
  unsigned short* wf1  = (unsigned short*)(ws + 144006464);    //     131,072
  unsigned short* wf2  = (unsigned short*)(ws + 144137536);    //      65,536
  float*          t1p  = (float*)(ws + 144203072);             //       2,048
  // total: 144,205,120 bytes
  // wf0 (131,072 B) uses the (now otherwise unused) head of the workspace.
  unsigned short* wf0  = (unsigned short*)(ws + 0);

  // zero only the histogram counters
  hipMemsetAsync(cnt1, 0, 800000, stream);

  hist_kernel<<<(NE + 255) / 256, 256, 0, stream>>>(ei, edel, esel, cnt1, cnt2);
  scan1_kernel<<<dim3(NB, 2), 256, 0, stream>>>(cnt1, cnt2, row1, row2, bsum);
  scan2_kernel<<<1, 512, 0, stream>>>(bsum, boff, ctr);
  scan3_kernel<<<dim3(NB, 2), 256, 0, stream>>>(row1, row2, cur1, cur2, boff);
  inv_kernel<<<NB, 256, 0, stream>>>(cnt1, cnt2, inv1, inv2);
  compact_kernel<<<(NE + 255) / 256, 256, 0, stream>>>(ei, edel, esel, cur1, cur2,
                                                       s1s, s2s);
  prep_w<<<26, 256, 0, stream>>>(ecW1, ecW2, ec1g, ec2g, ec1b, wf1, wf2, t1p);
  prep_w0<<<32, 256, 0, stream>>>(W0a, W0v, wf0);

  s0_kernel<<<dim3(782, 2), 256, 0, stream>>>(x, b0a, b0v, bn0g, bn0b, wf0, Xb);
  head_av<<<25000, 256, 0, stream>>>(Xb, fcaW, fcab, fcvW, fcvb,
                                     out + 2 * NN, out + 2 * NN + 100000);

  const int EGB = 1563;         // ceil(6250 chunks / 4 waves)

  for (int k = 0; k < 4; k++){
    const unsigned short* w1k = wf1 + (size_t)k * 16 * 64 * 8;
    const unsigned short* w2k = wf2 + (size_t)k * 8 * 64 * 8;
    const float* t1k = t1p + k * 128;
    const float* b2p = ec2b + k * 64;

    edge_pass<<<EGB, 256, 0, stream>>>(Xb, s1s, row1, cnt1, inv1, w1k, w2k,
                                       t1k, b2p, nullptr, nullptr, nullptr,
                                       Yb, 0, 0);
    const unsigned short* resid = (k == 0) ? nullptr : Xb;
    const float* bg = (k < 3) ? (bng + k * 64) : nullptr;
    const float* bb = (k < 3) ? (bnb + k * 64) : nullptr;
    edge_pass<<<EGB, 256, 0, stream>>>(Yb, s2s, row2, cnt2, inv2, w1k, w2k,
                                       t1k, b2p, resid, bg, bb,
                                       Xb, (k == 0) ? 0 : 1, (k < 3) ? 1 : 0);
  }

  head_final<<<25000, 256, 0, stream>>>(Xb, fcW, fcb, out);
}

// Round 4
// 878.992 us; speedup vs baseline: 1.1009x; 1.0695x over previous
//
#include <hip/hip_runtime.h>

// ---------------------------------------------------------------------------
// GraphAllEdgeNet on MI355X — round 6: round-4 fused structure (verified) +
//   * gather prefetch pipeline in edge_pass (src rows t+1, edge recs t+2
//     issued before GEMM1; latency hides under MFMA + accumulate)
//   * head_av folded into s0 epilogue (shfl_xor cross-q reduce)
//   * head_final folded into last edge_pass epilogue (dohead)
//   * inv fused into scan3; prep_w/prep_w0 merged (-4 dispatches total)
// NO cooperative launch (round-5 mega-kernel failed: suspected
// graph-capture-incompatible hipLaunchCooperativeKernel).
// MFMA layout (measured): mfma_f32_16x16x32_bf16
//   A[m=lane&15][k=(lane>>4)*8+j], B[k=(lane>>4)*8+j][n=lane&15],
//   C/D: col=lane&15, row=(lane>>4)*4+reg.
// ---------------------------------------------------------------------------

#define NN 100000
#define NE 800000
#define NB 391                 // ceil(NN/256)
#define BNS 0.9999950000374998f

typedef __attribute__((ext_vector_type(8))) short short8;
typedef __attribute__((ext_vector_type(4))) float f32x4;

__device__ __forceinline__ float bf_lo(unsigned u){ union{unsigned i; float f;} v; v.i = u << 16; return v.f; }
__device__ __forceinline__ float bf_hi(unsigned u){ union{unsigned i; float f;} v; v.i = u & 0xffff0000u; return v.f; }
__device__ __forceinline__ float bf2f(unsigned short u){ union{unsigned i; float f;} v; v.i = ((unsigned)u) << 16; return v.f; }
__device__ __forceinline__ unsigned short f2bf(float f){
  union{float f; unsigned i;} v; v.f = f;
  unsigned r = v.i + 0x7fffu + ((v.i >> 16) & 1u);   // RNE
  return (unsigned short)(r >> 16);
}
__device__ __forceinline__ unsigned packbf(float a, float b){
  return (unsigned)f2bf(a) | ((unsigned)f2bf(b) << 16);
}

// ---------------- preprocessing -------------------------------------------

__global__ __launch_bounds__(256) void hist_kernel(
    const int* __restrict__ ei, const int* __restrict__ edel,
    const int* __restrict__ esel, int* cnt1, int* cnt2)
{
  int e = blockIdx.x * 256 + threadIdx.x;
  if (e >= NE) return;
  int d = edel[e], s = esel[e], dst = ei[NE + e];
  if (d < 1) atomicAdd(cnt1 + dst, 1);
  if ((d >= 1 && d < 4) || s == 1) atomicAdd(cnt2 + dst, 1);
}

__global__ __launch_bounds__(256) void scan1_kernel(
    const int* __restrict__ cnt1, const int* __restrict__ cnt2,
    int* row1, int* row2, int* bsum)
{
  const int a = blockIdx.y;
  const int* cnt = a ? cnt2 : cnt1;
  int* row = a ? row2 : row1;
  int t = threadIdx.x, b = blockIdx.x, i = b * 256 + t;
  int v = (i < NN) ? cnt[i] : 0;
  __shared__ int sc[256];
  sc[t] = v; __syncthreads();
#pragma unroll
  for (int off = 1; off < 256; off <<= 1){
    int x = (t >= off) ? sc[t - off] : 0;
    __syncthreads();
    sc[t] += x;
    __syncthreads();
  }
  if (i < NN) row[i] = sc[t] - v;
  if (t == 255) bsum[a * 400 + b] = sc[t];
}

__global__ __launch_bounds__(512) void scan2_kernel(int* bsum, int* boff, int* ctr)
{
  int t = threadIdx.x;
  __shared__ int sc[512];
  for (int a = 0; a < 2; a++){
    int v = (t < NB) ? bsum[a * 400 + t] : 0;
    __syncthreads();
    sc[t] = v; __syncthreads();
#pragma unroll
    for (int off = 1; off < 512; off <<= 1){
      int x = (t >= off) ? sc[t - off] : 0;
      __syncthreads();
      sc[t] += x;
      __syncthreads();
    }
    if (t < NB) boff[a * 400 + t] = sc[t] - v;
    if (t == NB - 1) ctr[a] = sc[t];
  }
}

// scan finalize + inv (fused)
__global__ __launch_bounds__(256) void scan3_kernel(
    int* row1, int* row2, int* cur1, int* cur2, const int* __restrict__ boff,
    const int* __restrict__ cnt1, const int* __restrict__ cnt2,
    float* inv1, float* inv2)
{
  const int a = blockIdx.y;
  int* row = a ? row2 : row1;
  int* cur = a ? cur2 : cur1;
  int i = blockIdx.x * 256 + threadIdx.x;
  if (i >= NN) return;
  int r = row[i] + boff[a * 400 + blockIdx.x];
  row[i] = r;
  cur[i] = r;
  if (a == 0) inv1[i] = 1.f / fmaxf((float)cnt1[i], 1.f);
  else        inv2[i] = 1.f / fmaxf((float)cnt2[i], 1.f);
}

// compacted edge record: src | (dst&15)<<20  (src < 2^17; chunk = dst>>4)
__global__ __launch_bounds__(256) void compact_kernel(
    const int* __restrict__ ei, const int* __restrict__ edel,
    const int* __restrict__ esel, int* cur1, int* cur2,
    int* s1s, int* s2s)
{
  int e = blockIdx.x * 256 + threadIdx.x;
  if (e >= NE) return;
  int d = edel[e], s = esel[e], src = ei[e], dst = ei[NE + e];
  int rec = src | ((dst & 15) << 20);
  if (d < 1){ int p = atomicAdd(cur1 + dst, 1); s1s[p] = rec; }
  if ((d >= 1 && d < 4) || s == 1){ int p = atomicAdd(cur2 + dst, 1); s2s[p] = rec; }
}

// merged weight prep:
//  g <  6144: wf1 [k][frag f=t*4+h][lane][8] (BN1 row-scale, BN2 col-scale folded)
//             wf2 [k][frag f=t*2+h][lane][8]
//  g <  6656: t1p [k][128] = b1 / (BNS*g1)
//  g < 14848: wf0 [tt][ks][t][lane][8]
__global__ __launch_bounds__(256) void prep_all(
    const float* __restrict__ W1, const float* __restrict__ W2,
    const float* __restrict__ g1, const float* __restrict__ g2,
    const float* __restrict__ b1,
    const float* __restrict__ W0a, const float* __restrict__ W0v,
    unsigned short* __restrict__ wf1, unsigned short* __restrict__ wf2,
    float* __restrict__ t1p, unsigned short* __restrict__ wf0)
{
  int g = blockIdx.x * 256 + threadIdx.x;
  if (g >= 14848) return;
  if (g >= 6656){                       // wf0 part
    int gg = g - 6656;
    int l = gg & 63, t = (gg >> 6) & 3, ks = (gg >> 8) & 15, tt = (gg >> 12) & 1;
    const float* W = tt ? W0v : W0a;
    int c = t * 16 + (l & 15);
    int kb = ks * 32 + (l >> 4) * 8;
    unsigned short* o = wf0 + (size_t)gg * 8;
#pragma unroll
    for (int j = 0; j < 8; j++) o[j] = f2bf(W[(kb + j) * 64 + c]);
    return;
  }
  if (g >= 6144){                       // t1p part
    int i = g - 6144;
    int k = i >> 7, c = i & 127;
    t1p[i] = b1[k * 128 + c] / (BNS * g1[k * 128 + c]);
    return;
  }
  int k = g / 1536, r = g % 1536, f = r >> 6, l = r & 63;
  int q = l >> 4, m = l & 15;
  if (f < 16){
    int t = f >> 2, h = f & 3;
    unsigned short* o = wf1 + (((size_t)k * 16 + f) * 64 + l) * 8;
    const float* Wk = W1 + k * 8192;
    int cp = t * 16 + m;
    float cs = BNS * g2[k * 64 + cp];
#pragma unroll
    for (int j = 0; j < 8; j++){
      int kg = h * 32 + q * 8 + j;
      float w, rs;
      if (kg < 64){
        w  = Wk[(64 + kg) * 64 + cp];
        rs = BNS * g1[k * 128 + 64 + kg];
      } else {
        w  = Wk[(kg - 64) * 64 + cp];
        rs = BNS * g1[k * 128 + kg - 64];
      }
      o[j] = f2bf(w * rs * cs);
    }
  } else {
    int f2 = f - 16, t = f2 >> 1, h = f2 & 1;
    unsigned short* o = wf2 + (((size_t)k * 8 + f2) * 64 + l) * 8;
    const float* Wk = W2 + k * 4096;
#pragma unroll
    for (int j = 0; j < 8; j++){
      int kg = h * 32 + q * 8 + j;
      o[j] = f2bf(Wk[kg * 64 + t * 16 + m]);
    }
  }
}

// ---------------- stage 0: node projection + A/V heads --------------------
// One wave per 16 nodes; K=512 in 16 steps of 32. Epilogue folds bias+BN0+
// ReLU, stores bf16 feats, and computes the per-node A/V head via cross-q
// shfl_xor reduction (channels t*16+q*4+r live in lane (q<<4)|m16).

__global__ __launch_bounds__(256) void s0_kernel(
    const float* __restrict__ x,
    const float* __restrict__ b0a, const float* __restrict__ b0v,
    const float* __restrict__ bn0g, const float* __restrict__ bn0b,
    const unsigned short* __restrict__ wf0,
    const float* __restrict__ fcaW, const float* __restrict__ fcab,
    const float* __restrict__ fcvW, const float* __restrict__ fcvb,
    unsigned short* __restrict__ Xb, float* __restrict__ outA,
    float* __restrict__ outV)
{
  const int tt = blockIdx.y;
  const int wv = threadIdx.x >> 6;
  const int l  = threadIdx.x & 63;
  const int q = l >> 4, m16 = l & 15;
  const int wid = blockIdx.x * 4 + wv;
  if (wid >= 3125) return;
  const int node = wid * 16 + m16;
  const float* bias = tt ? b0v : b0a;
  const float* WH = tt ? fcvW : fcaW;

  float fs[4][4], ft[4][4];
#pragma unroll
  for (int t = 0; t < 4; t++)
#pragma unroll
    for (int r = 0; r < 4; r++){
      int c = t * 16 + q * 4 + r;
      float s = BNS * bn0g[c];
      fs[t][r] = s;
      ft[t][r] = bias[c] * s + bn0b[c];
    }

  const unsigned short* wbase = wf0 + (size_t)tt * 32768;
  const float* xp = x + (size_t)(2 * node + tt) * 1024 + tt * 512 + q * 8;

  f32x4 acc[4];
#pragma unroll
  for (int t = 0; t < 4; t++) acc[t] = (f32x4){0.f, 0.f, 0.f, 0.f};

  for (int ks = 0; ks < 16; ks++){
    float4 xa = *(const float4*)(xp + ks * 32);
    float4 xb = *(const float4*)(xp + ks * 32 + 4);
    union { unsigned u4[4]; short8 s8; } bb;
    bb.u4[0] = packbf(xa.x, xa.y);
    bb.u4[1] = packbf(xa.z, xa.w);
    bb.u4[2] = packbf(xb.x, xb.y);
    bb.u4[3] = packbf(xb.z, xb.w);
    const unsigned short* wk = wbase + (size_t)ks * 2048 + l * 8;
#pragma unroll
    for (int t = 0; t < 4; t++){
      short8 a = *(const short8*)(wk + t * 512);
      acc[t] = __builtin_amdgcn_mfma_f32_16x16x32_bf16(a, bb.s8, acc[t], 0, 0, 0);
    }
  }

  const int i2 = 2 * node + tt;
  unsigned short* op = Xb + (size_t)i2 * 64 + (q << 2);
  float p0 = 0.f, p1 = 0.f;
#pragma unroll
  for (int t = 0; t < 4; t++){
    float v[4];
#pragma unroll
    for (int r = 0; r < 4; r++)
      v[r] = fmaxf(fmaf(acc[t][r], fs[t][r], ft[t][r]), 0.f);
    uint2 w; w.x = packbf(v[0], v[1]); w.y = packbf(v[2], v[3]);
    *(uint2*)(op + t * 16) = w;
#pragma unroll
    for (int r = 0; r < 4; r++){
      float2 wh = *(const float2*)(WH + 2 * (t * 16 + q * 4 + r));
      p0 = fmaf(v[r], wh.x, p0);
      p1 = fmaf(v[r], wh.y, p1);
    }
  }
  p0 += __shfl_xor(p0, 16); p0 += __shfl_xor(p0, 32);
  p1 += __shfl_xor(p1, 16); p1 += __shfl_xor(p1, 32);
  if (q == 0){
    const float* bh = tt ? fcvb : fcab;
    float* o = (tt ? outV : outA) + node * 2;
    o[0] = p0 + bh[0];
    o[1] = p1 + bh[1];
  }
}

// ---------------- fused EdgeConv pass (prefetch-pipelined) ----------------
// One wave per 16 dst nodes (dst-sorted edges -> contiguous range).
// Tile loop: [use prefetched src rows] gather-compute -> write rt ->
// [prefetch rows t+1, recs t+2] -> GEMM1 -> z-tile -> in-reg segmented acc.
// Epilogue: mean -> GEMM2 -> (+resid)(+BN,ReLU) -> store OR final head.

__global__ __launch_bounds__(256, 3) void edge_pass(
    const unsigned short* __restrict__ fin,
    const int* __restrict__ spk,
    const int* __restrict__ row, const int* __restrict__ cnt,
    const float* __restrict__ inv,
    const unsigned short* __restrict__ wf1,
    const unsigned short* __restrict__ wf2,
    const float* __restrict__ t1p,
    const float* __restrict__ bn2b,
    const unsigned short* resid,           // may alias outb (same-lane RMW)
    const float* __restrict__ bng, const float* __restrict__ bnb,
    unsigned short* __restrict__ outb, int hasres, int hasbn,
    const float* __restrict__ fcW, const float* __restrict__ fcb,
    float* __restrict__ outh, int dohead)
{
  const int tid = threadIdx.x;
  const int l = tid & 63;
  const int wv = tid >> 6;
  const int q = l >> 4, m16 = l & 15;
  const int ge = l >> 2, gc0 = (l & 3) << 4;

  __shared__ unsigned short wlds[8192];          // 16 KB wf1 tile (block)
  __shared__ unsigned short rt_s[4][16 * 136];   // B-tile  [edge][128+8]
  __shared__ unsigned short zt_s[4][16 * 72];    // z-tile  [edge][64+8]
  __shared__ unsigned short xi_s[4][16 * 72];    // raw xi  [node][64+8]

  {
    const uint4* s4 = (const uint4*)wf1;
    uint4* d4 = (uint4*)wlds;
#pragma unroll
    for (int i = 0; i < 4; i++) d4[tid + 256 * i] = s4[tid + 256 * i];
  }
  __syncthreads();

  int chunk = blockIdx.x * 4 + wv;
  const bool active = chunk < 6250;
  if (chunk > 6249) chunk = 6249;
  const int d0c = chunk << 4;
  const int nd = d0c + ge;

  unsigned short* rt = rt_s[wv];
  unsigned short* zt = zt_s[wv];
  unsigned short* xi = xi_s[wv];

  const int rlo = row[nd], deg = cnt[nd];
  const float ivd = inv[nd];

  float t1a[16], t1b[16];
#pragma unroll
  for (int j0 = 0; j0 < 16; j0 += 4){
    *(float4*)(t1a + j0) = *(const float4*)(t1p + gc0 + j0);
    *(float4*)(t1b + j0) = *(const float4*)(t1p + 64 + gc0 + j0);
  }
  f32x4 t2v[4];
#pragma unroll
  for (int t = 0; t < 4; t++)
    t2v[t] = *(const f32x4*)(bn2b + t * 16 + (q << 2));

  {
    const uint4* px = (const uint4*)(fin + (size_t)nd * 64 + gc0);
    uint4 u0 = px[0], u1 = px[1];
    unsigned short* wr = xi + ge * 72 + gc0;
    *(uint4*)(wr)     = u0;
    *(uint4*)(wr + 8) = u1;
  }

  const int r_begin = __shfl(rlo, 0);
  const int r_end   = __shfl(rlo + deg, 63);

  float s[16];
#pragma unroll
  for (int j = 0; j < 16; j++) s[j] = 0.f;

  __builtin_amdgcn_wave_barrier();   // xi_s visible to gather roles

  if (r_begin < r_end){
    // prologue of the prefetch pipeline
    int eg0 = r_begin + ge; if (eg0 >= r_end) eg0 = r_end - 1;
    int vc = spk[eg0];
    const uint4* pr0 = (const uint4*)(fin + (size_t)(vc & 0xFFFFF) * 64 + gc0);
    uint4 cA = pr0[0], cB = pr0[1];
    int vn = vc;
    if (r_begin + 16 < r_end){
      int eg1 = r_begin + 16 + ge; if (eg1 >= r_end) eg1 = r_end - 1;
      vn = spk[eg1];
    }

    for (int e0 = r_begin; e0 < r_end; e0 += 16){
      // ---- gather compute (rows already in cA/cB) -> rt tile
      const int d15 = (vc >> 20) & 15;
      const uint4* pxi = (const uint4*)(xi + d15 * 72 + gc0);
      uint4 xu0 = pxi[0], xu1 = pxi[1];
      unsigned sa[8] = {cA.x,cA.y,cA.z,cA.w,cB.x,cB.y,cB.z,cB.w};
      unsigned xa8[8] = {xu0.x,xu0.y,xu0.z,xu0.w,xu1.x,xu1.y,xu1.z,xu1.w};
      unsigned rb[8], rc[8];
#pragma unroll
      for (int p8 = 0; p8 < 8; p8++){
        float x0 = bf_lo(xa8[p8]), x1 = bf_hi(xa8[p8]);
        float e0f = bf_lo(sa[p8]) - x0, e1f = bf_hi(sa[p8]) - x1;
        rb[p8] = packbf(fmaxf(e0f + t1b[2*p8],   0.f),
                        fmaxf(e1f + t1b[2*p8+1], 0.f));
        rc[p8] = packbf(fmaxf(x0 + t1a[2*p8],   0.f),
                        fmaxf(x1 + t1a[2*p8+1], 0.f));
      }
      unsigned short* wr = rt + ge * 136 + gc0;
      { uint4 u; u.x=rb[0]; u.y=rb[1]; u.z=rb[2]; u.w=rb[3]; *(uint4*)(wr)      = u; }
      { uint4 u; u.x=rb[4]; u.y=rb[5]; u.z=rb[6]; u.w=rb[7]; *(uint4*)(wr + 8)  = u; }
      { uint4 u; u.x=rc[0]; u.y=rc[1]; u.z=rc[2]; u.w=rc[3]; *(uint4*)(wr + 64) = u; }
      { uint4 u; u.x=rc[4]; u.y=rc[5]; u.z=rc[6]; u.w=rc[7]; *(uint4*)(wr + 72) = u; }

      // ---- prefetch next tile (loads fly during GEMM1 + accumulate)
      uint4 nA = cA, nB = cB; int vn2 = vn;
      if (e0 + 16 < r_end){
        const uint4* pn = (const uint4*)(fin + (size_t)(vn & 0xFFFFF) * 64 + gc0);
        nA = pn[0]; nB = pn[1];
        if (e0 + 32 < r_end){
          int eg2 = e0 + 32 + ge; if (eg2 >= r_end) eg2 = r_end - 1;
          vn2 = spk[eg2];
        }
      }

      __builtin_amdgcn_wave_barrier();

      // ---- GEMM1 (K=128, scales folded) + b2/relu -> z tile
      const unsigned short* rrow = rt + m16 * 136 + q * 8;
      short8 b1[4];
#pragma unroll
      for (int h = 0; h < 4; h++) b1[h] = *(const short8*)(rrow + h * 32);
#pragma unroll
      for (int t = 0; t < 4; t++){
        f32x4 c = {0.f, 0.f, 0.f, 0.f};
#pragma unroll
        for (int h = 0; h < 4; h++){
          short8 a = *(const short8*)(wlds + ((t * 4 + h) * 64 + l) * 8);
          c = __builtin_amdgcn_mfma_f32_16x16x32_bf16(a, b1[h], c, 0, 0, 0);
        }
        uint2 w;
        w.x = packbf(fmaxf(c[0] + t2v[t][0], 0.f), fmaxf(c[1] + t2v[t][1], 0.f));
        w.y = packbf(fmaxf(c[2] + t2v[t][2], 0.f), fmaxf(c[3] + t2v[t][3], 0.f));
        *(uint2*)(zt + m16 * 72 + t * 16 + (q << 2)) = w;
      }

      __builtin_amdgcn_wave_barrier();

      // ---- segmented accumulation (lane's node rows within this tile)
      int jlo = rlo - e0;       if (jlo < 0)  jlo = 0;
      int jhi = rlo + deg - e0; if (jhi > 16) jhi = 16;
      for (int j = jlo; j < jhi; j++){
        const uint4* pz = (const uint4*)(zt + j * 72 + gc0);
        uint4 z0 = pz[0], z1 = pz[1];
        unsigned za[8] = {z0.x,z0.y,z0.z,z0.w,z1.x,z1.y,z1.z,z1.w};
#pragma unroll
        for (int p8 = 0; p8 < 8; p8++){
          s[2*p8]   += bf_lo(za[p8]);
          s[2*p8+1] += bf_hi(za[p8]);
        }
      }
      __builtin_amdgcn_wave_barrier();

      cA = nA; cB = nB; vc = vn; vn = vn2;
    }
  }

  // ---- epilogue: mean -> GEMM2 -> (+resid)(+BN,ReLU) -> store / head
  unsigned pk[8];
#pragma unroll
  for (int p8 = 0; p8 < 8; p8++) pk[p8] = packbf(s[2*p8] * ivd, s[2*p8+1] * ivd);
  unsigned short* wr = zt + ge * 72 + gc0;
  { uint4 u; u.x=pk[0]; u.y=pk[1]; u.z=pk[2]; u.w=pk[3]; *(uint4*)(wr)     = u; }
  { uint4 u; u.x=pk[4]; u.y=pk[5]; u.z=pk[6]; u.w=pk[7]; *(uint4*)(wr + 8) = u; }

  __builtin_amdgcn_wave_barrier();

  short8 a2[4][2];
#pragma unroll
  for (int t = 0; t < 4; t++)
#pragma unroll
    for (int h = 0; h < 2; h++)
      a2[t][h] = *(const short8*)(wf2 + (((size_t)(t * 2 + h)) * 64 + l) * 8);

  const unsigned short* r2row = zt + m16 * 72 + q * 8;
  short8 b2[2];
  b2[0] = *(const short8*)(r2row);
  b2[1] = *(const short8*)(r2row + 32);

  const int dn = d0c + m16;
  unsigned short* op = outb + (size_t)dn * 64 + (q << 2);
  float p0 = 0.f, p1 = 0.f;
#pragma unroll
  for (int t = 0; t < 4; t++){
    f32x4 c = {0.f, 0.f, 0.f, 0.f};
    c = __builtin_amdgcn_mfma_f32_16x16x32_bf16(a2[t][0], b2[0], c, 0, 0, 0);
    c = __builtin_amdgcn_mfma_f32_16x16x32_bf16(a2[t][1], b2[1], c, 0, 0, 0);
    float v[4] = {c[0], c[1], c[2], c[3]};
    if (hasres){
      uint2 rv = *(const uint2*)(resid + (size_t)dn * 64 + t * 16 + (q << 2));
      v[0] += bf_lo(rv.x); v[1] += bf_hi(rv.x);
      v[2] += bf_lo(rv.y); v[3] += bf_hi(rv.y);
    }
    if (hasbn){
      f32x4 g = *(const f32x4*)(bng + t * 16 + (q << 2));
      f32x4 b = *(const f32x4*)(bnb + t * 16 + (q << 2));
#pragma unroll
      for (int r = 0; r < 4; r++)
        v[r] = fmaxf(fmaf(v[r], BNS * g[r], b[r]), 0.f);
    }
    if (dohead){
#pragma unroll
      for (int r = 0; r < 4; r++){
        float2 wh = *(const float2*)(fcW + 2 * (t * 16 + q * 4 + r));
        p0 = fmaf(v[r], wh.x, p0);
        p1 = fmaf(v[r], wh.y, p1);
      }
    } else if (active){
      uint2 w; w.x = packbf(v[0], v[1]); w.y = packbf(v[2], v[3]);
      *(uint2*)(op + t * 16) = w;
    }
  }
  if (dohead){
    p0 += __shfl_xor(p0, 16); p0 += __shfl_xor(p0, 32);
    p1 += __shfl_xor(p1, 16); p1 += __shfl_xor(p1, 32);
    if (q == 0 && active){
      outh[dn * 2]     = p0 + fcb[0];
      outh[dn * 2 + 1] = p1 + fcb[1];
    }
  }
}

// ---------------- launcher -------------------------------------------------

extern "C" void kernel_launch(void* const* d_in, const int* in_sizes, int n_in,
                              void* d_out, int out_size, void* d_ws, size_t ws_size,
                              hipStream_t stream)
{
  const float* x    = (const float*)d_in[0];
  const int*   ei   = (const int*)d_in[1];
  const int*   edel = (const int*)d_in[2];
  const int*   esel = (const int*)d_in[3];
  // d_in[4] audio_node_mask: structurally (i%2==0); parity used directly.
  const float* W0a  = (const float*)d_in[5];
  const float* b0a  = (const float*)d_in[6];
  const float* W0v  = (const float*)d_in[7];
  const float* b0v  = (const float*)d_in[8];
  const float* bn0g = (const float*)d_in[9];
  const float* bn0b = (const float*)d_in[10];
  const float* ec1g = (const float*)d_in[11];
  const float* ec1b = (const float*)d_in[12];
  const float* ecW1 = (const float*)d_in[13];
  const float* ec2g = (const float*)d_in[14];
  const float* ec2b = (const float*)d_in[15];
  const float* ecW2 = (const float*)d_in[16];
  const float* bng  = (const float*)d_in[17];
  const float* bnb  = (const float*)d_in[18];
  const float* fcaW = (const float*)d_in[19];
  const float* fcab = (const float*)d_in[20];
  const float* fcvW = (const float*)d_in[21];
  const float* fcvb = (const float*)d_in[22];
  const float* fcW  = (const float*)d_in[23];
  const float* fcb  = (const float*)d_in[24];
  float* out = (float*)d_out;
  float* outA = out + 2 * NN;
  float* outV = out + 2 * NN + 100000;

  char* ws = (char*)d_ws;
  unsigned short* Xb   = (unsigned short*)(ws + 102400000);    //  12,800,000
  unsigned short* Yb   = (unsigned short*)(ws + 115200000);    //  12,800,000
  int*            s1s  = (int*)(ws + 128000000);               //   3,200,000
  int*            s2s  = (int*)(ws + 134400000);
  int*            cnt1 = (int*)(ws + 140800000);               //     400,000
  int*            cnt2 = (int*)(ws + 141200000);
  int*            row1 = (int*)(ws + 141600000);
  int*            row2 = (int*)(ws + 142000000);
  int*            cur1 = (int*)(ws + 142400000);
  int*            cur2 = (int*)(ws + 142800000);
  float*          inv1 = (float*)(ws + 143200000);
  float*          inv2 = (float*)(ws + 143600000);
  int*            bsum = (int*)(ws + 144000000);               //       3,200
  int*            boff = (int*)(ws + 144003200);               //       3,200
  int*            ctr  = (int*)(ws + 144006400);               //          64
  unsigned short* wf1  = (unsigned short*)(ws + 144006464);    //     131,072
  unsigned short* wf2  = (unsigned short*)(ws + 144137536);    //      65,536
  float*          t1p  = (float*)(ws + 144203072);             //       2,048
  // wf0 (131,072 B) uses the (otherwise unused) head of the workspace.
  unsigned short* wf0  = (unsigned short*)(ws + 0);

  hipMemsetAsync(cnt1, 0, 800000, stream);

  hist_kernel<<<(NE + 255) / 256, 256, 0, stream>>>(ei, edel, esel, cnt1, cnt2);
  scan1_kernel<<<dim3(NB, 2), 256, 0, stream>>>(cnt1, cnt2, row1, row2, bsum);
  scan2_kernel<<<1, 512, 0, stream>>>(bsum, boff, ctr);
  scan3_kernel<<<dim3(NB, 2), 256, 0, stream>>>(row1, row2, cur1, cur2, boff,
                                                cnt1, cnt2, inv1, inv2);
  compact_kernel<<<(NE + 255) / 256, 256, 0, stream>>>(ei, edel, esel, cur1, cur2,
                                                       s1s, s2s);
  prep_all<<<58, 256, 0, stream>>>(ecW1, ecW2, ec1g, ec2g, ec1b, W0a, W0v,
                                   wf1, wf2, t1p, wf0);

  s0_kernel<<<dim3(782, 2), 256, 0, stream>>>(x, b0a, b0v, bn0g, bn0b, wf0,
                                              fcaW, fcab, fcvW, fcvb,
                                              Xb, outA, outV);

  const int EGB = 1563;         // ceil(6250 chunks / 4 waves)

  for (int k = 0; k < 4; k++){
    const unsigned short* w1k = wf1 + (size_t)k * 16 * 64 * 8;
    const unsigned short* w2k = wf2 + (size_t)k * 8 * 64 * 8;
    const float* t1k = t1p + k * 128;
    const float* b2p = ec2b + k * 64;

    edge_pass<<<EGB, 256, 0, stream>>>(Xb, s1s, row1, cnt1, inv1, w1k, w2k,
                                       t1k, b2p, nullptr, nullptr, nullptr,
                                       Yb, 0, 0, nullptr, nullptr, nullptr, 0);
    const unsigned short* resid = (k == 0) ? nullptr : Xb;
    const float* bg = (k < 3) ? (bng + k * 64) : nullptr;
    const float* bb = (k < 3) ? (bnb + k * 64) : nullptr;
    const int dohead = (k == 3);
    edge_pass<<<EGB, 256, 0, stream>>>(Yb, s2s, row2, cnt2, inv2, w1k, w2k,
                                       t1k, b2p, resid, bg, bb,
                                       Xb, (k == 0) ? 0 : 1, (k < 3) ? 1 : 0,
                                       fcW, fcb, out, dohead);
  }
}